// Round 1
// baseline (2194.414 us; speedup 1.0000x reference)
//
#include <hip/hip_runtime.h>
#include <math.h>

// PointNet++ Set Abstraction: FPS -> ball query -> gather -> 3x(1x1conv+BN+ReLU) -> maxpool(K)
// Recompute pipeline (no big intermediates): ws ~19MB, deterministic (no float atomics).

static constexpr int BATCH  = 16;
static constexpr int NPTS   = 4096;
static constexpr int NPOINT = 1024;
static constexpr int NSAMP  = 32;
static constexpr int CIN    = 64;
static constexpr int C0IN   = 67;                    // 3 + CIN
static constexpr int ROWS   = BATCH * NPOINT * NSAMP; // 524288
static constexpr int TILE_R = 64;
static constexpr int NBLK   = ROWS / TILE_R;          // 8192

__device__ __forceinline__ float sqdist(float x, float y, float z,
                                        float cx, float cy, float cz) {
    // exact IEEE order: (dx*dx + dy*dy) + dz*dz, no fma contraction (matches reference f32)
    float dx = x - cx, dy = y - cy, dz = z - cz;
    return __fadd_rn(__fadd_rn(__fmul_rn(dx, dx), __fmul_rn(dy, dy)), __fmul_rn(dz, dz));
}

// ---------------- FPS: one block per batch, 256 threads x 16 points ----------------
__global__ __launch_bounds__(256) void fps_kernel(const float* __restrict__ xyz,
                                                  float* __restrict__ new_xyz) {
    const int b   = blockIdx.x;
    const int tid = threadIdx.x;
    const float* xb = xyz + (size_t)b * NPTS * 3;

    float px[16], py[16], pz[16], dist[16];
#pragma unroll
    for (int j = 0; j < 16; ++j) {
        int p = tid + j * 256;
        px[j] = xb[p * 3 + 0];
        py[j] = xb[p * 3 + 1];
        pz[j] = xb[p * 3 + 2];
        dist[j] = 1e10f;
    }
    __shared__ int   s_cent[NPOINT];
    __shared__ float s_rv[4];
    __shared__ int   s_ri[4];
    __shared__ int   s_far;

    int far = 0;
    for (int it = 0; it < NPOINT; ++it) {
        if (tid == 0) s_cent[it] = far;
        const float cx = xb[far * 3 + 0];
        const float cy = xb[far * 3 + 1];
        const float cz = xb[far * 3 + 2];
        float bv = -1.0f;
        int   bi = 0;
#pragma unroll
        for (int j = 0; j < 16; ++j) {
            float d  = sqdist(px[j], py[j], pz[j], cx, cy, cz);
            float nd = fminf(dist[j], d);   // jnp.minimum
            dist[j]  = nd;
            int p = tid + j * 256;          // ascending in j -> '>' keeps smallest index
            if (nd > bv) { bv = nd; bi = p; }
        }
        // wave argmax with first-index tie-break
#pragma unroll
        for (int m = 1; m < 64; m <<= 1) {
            float ov = __shfl_xor(bv, m);
            int   oi = __shfl_xor(bi, m);
            if (ov > bv || (ov == bv && oi < bi)) { bv = ov; bi = oi; }
        }
        const int wid = tid >> 6;
        if ((tid & 63) == 0) { s_rv[wid] = bv; s_ri[wid] = bi; }
        __syncthreads();
        if (tid == 0) {
            float v = s_rv[0]; int idx = s_ri[0];
#pragma unroll
            for (int w = 1; w < 4; ++w) {
                float ov = s_rv[w]; int oi = s_ri[w];
                if (ov > v || (ov == v && oi < idx)) { v = ov; idx = oi; }
            }
            s_far = idx;
        }
        __syncthreads();
        far = s_far;
    }
    for (int s = tid; s < NPOINT; s += 256) {
        int c = s_cent[s];
        new_xyz[((size_t)b * NPOINT + s) * 3 + 0] = xb[c * 3 + 0];
        new_xyz[((size_t)b * NPOINT + s) * 3 + 1] = xb[c * 3 + 1];
        new_xyz[((size_t)b * NPOINT + s) * 3 + 2] = xb[c * 3 + 2];
    }
}

// ---------------- ball query: one wave per (b,s) ----------------
__global__ __launch_bounds__(256) void ballq_kernel(const float* __restrict__ xyz,
                                                    const float* __restrict__ new_xyz,
                                                    int* __restrict__ gi) {
    const int lane = threadIdx.x & 63;
    const int w    = threadIdx.x >> 6;
    const int pair = blockIdx.x * 4 + w;   // b*NPOINT + s
    const int b    = pair >> 10;
    const float R2 = (float)(0.4 * 0.4);   // same double->f32 rounding as JAX
    const float* xb = xyz + (size_t)b * NPTS * 3;
    const float cx = new_xyz[pair * 3 + 0];
    const float cy = new_xyz[pair * 3 + 1];
    const float cz = new_xyz[pair * 3 + 2];
    int* g = gi + (size_t)pair * NSAMP;

    int found = 0, first = 0;
    bool have_first = false;
    for (int c0 = 0; c0 < NPTS; c0 += 64) {
        const int n = c0 + lane;
        float d = sqdist(xb[n * 3 + 0], xb[n * 3 + 1], xb[n * 3 + 2], cx, cy, cz);
        bool in = !(d > R2);               // keep iff sqr <= r^2
        unsigned long long m = __ballot(in);
        if (m) {
            if (!have_first) { first = c0 + (__ffsll(m) - 1); have_first = true; }
            if (in) {
                int slot = found + (int)__popcll(m & ((1ull << lane) - 1ull));
                if (slot < NSAMP) g[slot] = n;
            }
            found += (int)__popcll(m);
            if (found >= NSAMP) break;
        }
    }
    for (int slot = found + lane; slot < NSAMP; slot += 64) g[slot] = first;
}

// ---------------- fused MLP chain, recompute up to layer DEPTH ----------------
// DEPTH=0: y0 stats; DEPTH=1: y1 stats; DEPTH=2: y2 stats + max over K (pre-norm; BN+ReLU
// applied later — monotone since scale=g*rsqrt(v+eps) > 0 for g=1).
template <int DEPTH>
__global__ __launch_bounds__(256) void chain_kernel(
    const float* __restrict__ xyz, const float* __restrict__ points,
    const float* __restrict__ new_xyz, const int* __restrict__ gi,
    const float* __restrict__ w0, const float* __restrict__ b0,
    const float* __restrict__ w1, const float* __restrict__ b1,
    const float* __restrict__ w2, const float* __restrict__ b2,
    const float* __restrict__ ss,     // [3][2][128] scale/shift
    float* __restrict__ partial,      // [NBLK][2][Cd]
    float* __restrict__ maxy)         // [B*NPOINT][128]
{
    __shared__ __align__(16) float xw[TILE_R][68];
    __shared__ __align__(16) float wt[128][68];

    const int tid  = threadIdx.x;
    const int blk  = blockIdx.x;
    const int row0 = blk * TILE_R;
    const int ty = tid >> 4, tx = tid & 15;

    // gather input tile [64][67]: rel-xyz (3) + point feats (64)
    for (int idx = tid; idx < TILE_R * C0IN; idx += 256) {
        int r = idx / C0IN, c = idx - r * C0IN;
        int row = row0 + r;
        int bs  = row >> 5;
        int b   = bs >> 10;
        int n   = gi[row];
        float v;
        if (c < 3)
            v = xyz[((size_t)b * NPTS + n) * 3 + c] - new_xyz[(size_t)bs * 3 + c];
        else
            v = points[((size_t)b * NPTS + n) * CIN + (c - 3)];
        xw[r][c] = v;
    }
    for (int idx = tid; idx < 64 * C0IN; idx += 256) {
        int o = idx / C0IN, c = idx - o * C0IN;
        wt[o][c] = w0[idx];
    }
    __syncthreads();

    // ---- layer 0: 67 -> 64 ----
    float acc[4][4];
    {
        float bj[4];
#pragma unroll
        for (int j = 0; j < 4; ++j) bj[j] = b0[tx + 16 * j];
#pragma unroll
        for (int i = 0; i < 4; ++i)
#pragma unroll
            for (int j = 0; j < 4; ++j) acc[i][j] = bj[j];
    }
    for (int c4 = 0; c4 < 64; c4 += 4) {
        float4 xv[4], wv[4];
#pragma unroll
        for (int i = 0; i < 4; ++i) xv[i] = *(const float4*)&xw[ty + 16 * i][c4];
#pragma unroll
        for (int j = 0; j < 4; ++j) wv[j] = *(const float4*)&wt[tx + 16 * j][c4];
#pragma unroll
        for (int i = 0; i < 4; ++i)
#pragma unroll
            for (int j = 0; j < 4; ++j)
                acc[i][j] += xv[i].x * wv[j].x + xv[i].y * wv[j].y +
                             xv[i].z * wv[j].z + xv[i].w * wv[j].w;
    }
#pragma unroll
    for (int c = 64; c < C0IN; ++c) {
        float xv[4], wv[4];
#pragma unroll
        for (int i = 0; i < 4; ++i) xv[i] = xw[ty + 16 * i][c];
#pragma unroll
        for (int j = 0; j < 4; ++j) wv[j] = wt[tx + 16 * j][c];
#pragma unroll
        for (int i = 0; i < 4; ++i)
#pragma unroll
            for (int j = 0; j < 4; ++j) acc[i][j] += xv[i] * wv[j];
    }

    if (DEPTH == 0) {
        __syncthreads();
#pragma unroll
        for (int i = 0; i < 4; ++i)
#pragma unroll
            for (int j = 0; j < 4; ++j) xw[ty + 16 * i][tx + 16 * j] = acc[i][j];
        __syncthreads();
        if (tid < 64) {
            float s = 0.f, q = 0.f;
            for (int r = 0; r < TILE_R; ++r) { float v = xw[r][tid]; s += v; q += v * v; }
            partial[(size_t)blk * 128 + tid]      = s;
            partial[(size_t)blk * 128 + 64 + tid] = q;
        }
        return;
    }

    // norm0 + relu -> xw, load W1
    __syncthreads();
#pragma unroll
    for (int i = 0; i < 4; ++i)
#pragma unroll
        for (int j = 0; j < 4; ++j) {
            int o = tx + 16 * j;
            float h = acc[i][j] * ss[o] + ss[128 + o];
            xw[ty + 16 * i][o] = fmaxf(h, 0.f);
        }
    for (int idx = tid; idx < 64 * 64; idx += 256) {
        int o = idx >> 6, c = idx & 63;
        wt[o][c] = w1[idx];
    }
    __syncthreads();

    // ---- layer 1: 64 -> 64 ----
    {
        float bj[4];
#pragma unroll
        for (int j = 0; j < 4; ++j) bj[j] = b1[tx + 16 * j];
#pragma unroll
        for (int i = 0; i < 4; ++i)
#pragma unroll
            for (int j = 0; j < 4; ++j) acc[i][j] = bj[j];
    }
    for (int c4 = 0; c4 < 64; c4 += 4) {
        float4 xv[4], wv[4];
#pragma unroll
        for (int i = 0; i < 4; ++i) xv[i] = *(const float4*)&xw[ty + 16 * i][c4];
#pragma unroll
        for (int j = 0; j < 4; ++j) wv[j] = *(const float4*)&wt[tx + 16 * j][c4];
#pragma unroll
        for (int i = 0; i < 4; ++i)
#pragma unroll
            for (int j = 0; j < 4; ++j)
                acc[i][j] += xv[i].x * wv[j].x + xv[i].y * wv[j].y +
                             xv[i].z * wv[j].z + xv[i].w * wv[j].w;
    }

    if (DEPTH == 1) {
        __syncthreads();
#pragma unroll
        for (int i = 0; i < 4; ++i)
#pragma unroll
            for (int j = 0; j < 4; ++j) xw[ty + 16 * i][tx + 16 * j] = acc[i][j];
        __syncthreads();
        if (tid < 64) {
            float s = 0.f, q = 0.f;
            for (int r = 0; r < TILE_R; ++r) { float v = xw[r][tid]; s += v; q += v * v; }
            partial[(size_t)blk * 128 + tid]      = s;
            partial[(size_t)blk * 128 + 64 + tid] = q;
        }
        return;
    }

    // norm1 + relu -> xw, load W2
    __syncthreads();
#pragma unroll
    for (int i = 0; i < 4; ++i)
#pragma unroll
        for (int j = 0; j < 4; ++j) {
            int o = tx + 16 * j;
            float h = acc[i][j] * ss[256 + o] + ss[256 + 128 + o];
            xw[ty + 16 * i][o] = fmaxf(h, 0.f);
        }
    for (int idx = tid; idx < 128 * 64; idx += 256) {
        int o = idx >> 6, c = idx & 63;
        wt[o][c] = w2[idx];
    }
    __syncthreads();

    // ---- layer 2: 64 -> 128 ----
    float acc2[4][8];
    {
        float bj[8];
#pragma unroll
        for (int j = 0; j < 8; ++j) bj[j] = b2[tx + 16 * j];
#pragma unroll
        for (int i = 0; i < 4; ++i)
#pragma unroll
            for (int j = 0; j < 8; ++j) acc2[i][j] = bj[j];
    }
    for (int c4 = 0; c4 < 64; c4 += 4) {
        float4 xv[4], wv[8];
#pragma unroll
        for (int i = 0; i < 4; ++i) xv[i] = *(const float4*)&xw[ty + 16 * i][c4];
#pragma unroll
        for (int j = 0; j < 8; ++j) wv[j] = *(const float4*)&wt[tx + 16 * j][c4];
#pragma unroll
        for (int i = 0; i < 4; ++i)
#pragma unroll
            for (int j = 0; j < 8; ++j)
                acc2[i][j] += xv[i].x * wv[j].x + xv[i].y * wv[j].y +
                              xv[i].z * wv[j].z + xv[i].w * wv[j].w;
    }

    // stats + max over K (rows 0..31 = group 2*blk, rows 32..63 = group 2*blk+1)
    const int bs0 = blk * 2;
#pragma unroll
    for (int half = 0; half < 2; ++half) {
        __syncthreads();
#pragma unroll
        for (int i = 0; i < 4; ++i)
#pragma unroll
            for (int jj = 0; jj < 4; ++jj) {
                int j = half * 4 + jj;
                xw[ty + 16 * i][tx + 16 * jj] = acc2[i][j];
            }
        __syncthreads();
        if (tid < 64) {
            float s = 0.f, q = 0.f, m0 = -1e30f, m1 = -1e30f;
            for (int r = 0; r < 32; ++r)  { float v = xw[r][tid]; s += v; q += v * v; m0 = fmaxf(m0, v); }
            for (int r = 32; r < 64; ++r) { float v = xw[r][tid]; s += v; q += v * v; m1 = fmaxf(m1, v); }
            int cg = half * 64 + tid;
            partial[(size_t)blk * 256 + cg]        = s;
            partial[(size_t)blk * 256 + 128 + cg]  = q;
            maxy[(size_t)bs0 * 128 + cg]           = m0;
            maxy[(size_t)(bs0 + 1) * 128 + cg]     = m1;
        }
    }
}

// ---------------- reduce stats -> scale/shift ----------------
__global__ __launch_bounds__(256) void reduce_stats_kernel(
    const float* __restrict__ partial, int Cd, float inv_count,
    const float* __restrict__ g, const float* __restrict__ be,
    float* __restrict__ ss_layer) {
    const int c   = blockIdx.x;
    const int tid = threadIdx.x;
    float s = 0.f, q = 0.f;
    for (int blk = tid; blk < NBLK; blk += 256) {
        s += partial[(size_t)blk * 2 * Cd + c];
        q += partial[(size_t)blk * 2 * Cd + Cd + c];
    }
#pragma unroll
    for (int m = 1; m < 64; m <<= 1) { s += __shfl_xor(s, m); q += __shfl_xor(q, m); }
    __shared__ float ls[4], lq[4];
    const int wid = tid >> 6;
    if ((tid & 63) == 0) { ls[wid] = s; lq[wid] = q; }
    __syncthreads();
    if (tid == 0) {
        s = ls[0] + ls[1] + ls[2] + ls[3];
        q = lq[0] + lq[1] + lq[2] + lq[3];
        float mean = s * inv_count;
        float var  = q * inv_count - mean * mean;   // biased var
        float sc   = g[c] / sqrtf(var + 1e-5f);
        ss_layer[c]       = sc;
        ss_layer[128 + c] = be[c] - mean * sc;
    }
}

// ---------------- final: BN2 + ReLU applied to max-pooled y2 ----------------
__global__ __launch_bounds__(256) void final_kernel(const float* __restrict__ maxy,
                                                    const float* __restrict__ ss2,
                                                    float* __restrict__ outp) {
    int idx = blockIdx.x * 256 + threadIdx.x;   // B*NPOINT*128
    int c = idx & 127;
    float v = maxy[idx] * ss2[c] + ss2[128 + c];
    outp[idx] = fmaxf(v, 0.f);
}

extern "C" void kernel_launch(void* const* d_in, const int* in_sizes, int n_in,
                              void* d_out, int out_size, void* d_ws, size_t ws_size,
                              hipStream_t stream) {
    const float* xyz    = (const float*)d_in[0];
    const float* points = (const float*)d_in[1];
    const float* w0 = (const float*)d_in[2];  const float* b0  = (const float*)d_in[3];
    const float* g0 = (const float*)d_in[4];  const float* be0 = (const float*)d_in[5];
    const float* w1 = (const float*)d_in[6];  const float* b1  = (const float*)d_in[7];
    const float* g1 = (const float*)d_in[8];  const float* be1 = (const float*)d_in[9];
    const float* w2 = (const float*)d_in[10]; const float* b2  = (const float*)d_in[11];
    const float* g2 = (const float*)d_in[12]; const float* be2 = (const float*)d_in[13];

    float* out      = (float*)d_out;
    float* new_xyz  = out;                                 // [B, S, 3]
    float* out_pts  = out + (size_t)BATCH * NPOINT * 3;    // [B, S, 128]

    char* p = (char*)d_ws;
    int* gi = (int*)p;          p += (((size_t)ROWS * 4) + 255) & ~(size_t)255;
    float* partial = (float*)p; p += (((size_t)NBLK * 256 * 4) + 255) & ~(size_t)255;
    float* ss = (float*)p;      p += ((size_t)(3 * 256 * 4) + 255) & ~(size_t)255;
    float* maxy = (float*)p;    // [B*NPOINT][128] = 8 MB

    const float inv_count = 1.0f / (float)ROWS;

    fps_kernel<<<BATCH, 256, 0, stream>>>(xyz, new_xyz);
    ballq_kernel<<<(BATCH * NPOINT) / 4, 256, 0, stream>>>(xyz, new_xyz, gi);

    chain_kernel<0><<<NBLK, 256, 0, stream>>>(xyz, points, new_xyz, gi,
                                              w0, b0, w1, b1, w2, b2, ss, partial, maxy);
    reduce_stats_kernel<<<64, 256, 0, stream>>>(partial, 64, inv_count, g0, be0, ss + 0);

    chain_kernel<1><<<NBLK, 256, 0, stream>>>(xyz, points, new_xyz, gi,
                                              w0, b0, w1, b1, w2, b2, ss, partial, maxy);
    reduce_stats_kernel<<<64, 256, 0, stream>>>(partial, 64, inv_count, g1, be1, ss + 256);

    chain_kernel<2><<<NBLK, 256, 0, stream>>>(xyz, points, new_xyz, gi,
                                              w0, b0, w1, b1, w2, b2, ss, partial, maxy);
    reduce_stats_kernel<<<128, 256, 0, stream>>>(partial, 128, inv_count, g2, be2, ss + 512);

    final_kernel<<<(BATCH * NPOINT * 128) / 256, 256, 0, stream>>>(maxy, ss + 512, out_pts);
}

// Round 2
// 1618.541 us; speedup vs baseline: 1.3558x; 1.3558x over previous
//
#include <hip/hip_runtime.h>
#include <math.h>

// PointNet++ SA: FPS -> ball query -> gather -> 3x(1x1conv+BN+ReLU) -> maxpool(K)
// R1: fps v2 (1 barrier/iter, u64 packed argmax); layer0 factorized as P[n]-Q[s].

static constexpr int BATCH  = 16;
static constexpr int NPTS   = 4096;
static constexpr int NPOINT = 1024;
static constexpr int NSAMP  = 32;
static constexpr int CIN    = 64;
static constexpr int ROWS   = BATCH * NPOINT * NSAMP;  // 524288
static constexpr int NBLK   = ROWS / 64;               // 8192

__device__ __forceinline__ float sqdist(float x, float y, float z,
                                        float cx, float cy, float cz) {
    // exact IEEE order: (dx*dx + dy*dy) + dz*dz, no fma contraction (matches reference f32)
    float dx = x - cx, dy = y - cy, dz = z - cz;
    return __fadd_rn(__fadd_rn(__fmul_rn(dx, dx), __fmul_rn(dy, dy)), __fmul_rn(dz, dz));
}

// ---------------- FPS v2: 1024 thr, u64 packed argmax, 1 barrier/iter ----------------
__global__ __launch_bounds__(1024) void fps_kernel(const float* __restrict__ xyz,
                                                   float* __restrict__ new_xyz) {
    const int b   = blockIdx.x;
    const int tid = threadIdx.x;
    const float* xb = xyz + (size_t)b * NPTS * 3;
    __shared__ float sx[NPTS], sy[NPTS], sz[NPTS];
    __shared__ int   s_cent[NPOINT];
    __shared__ unsigned long long s_red[2][16];

    for (int p = tid; p < NPTS; p += 1024) {
        sx[p] = xb[p * 3 + 0]; sy[p] = xb[p * 3 + 1]; sz[p] = xb[p * 3 + 2];
    }
    __syncthreads();
    float px[4], py[4], pz[4], dist[4];
#pragma unroll
    for (int j = 0; j < 4; ++j) {
        int p = tid + j * 1024;
        px[j] = sx[p]; py[j] = sy[p]; pz[j] = sz[p]; dist[j] = 1e10f;
    }
    const int lane = tid & 63, wid = tid >> 6;
    int far = 0;
    for (int it = 0; it < NPOINT; ++it) {
        if (tid == 0) s_cent[it] = far;
        const float cx = sx[far], cy = sy[far], cz = sz[far];
        unsigned long long best = 0;
#pragma unroll
        for (int j = 0; j < 4; ++j) {
            float d  = sqdist(px[j], py[j], pz[j], cx, cy, cz);
            float nd = fminf(dist[j], d);       // jnp.minimum
            dist[j]  = nd;
            // pack: high=dist bits (>=0 -> monotonic), low=4095-idx (tie -> smallest idx)
            unsigned long long u = ((unsigned long long)__float_as_uint(nd) << 32)
                                 | (unsigned)(4095 - (tid + j * 1024));
            best = (u > best) ? u : best;
        }
#pragma unroll
        for (int m = 1; m < 64; m <<= 1) {
            unsigned long long o = __shfl_xor(best, m);
            best = (o > best) ? o : best;
        }
        if (lane == 0) s_red[it & 1][wid] = best;
        __syncthreads();
        unsigned long long w = s_red[it & 1][0];
#pragma unroll
        for (int k = 1; k < 16; ++k) {
            unsigned long long o = s_red[it & 1][k];
            w = (o > w) ? o : w;
        }
        far = 4095 - (int)(w & 0xffffffffu);
    }
    __syncthreads();
    if (tid < NPOINT) {
        int c = s_cent[tid];
        new_xyz[((size_t)b * NPOINT + tid) * 3 + 0] = sx[c];
        new_xyz[((size_t)b * NPOINT + tid) * 3 + 1] = sy[c];
        new_xyz[((size_t)b * NPOINT + tid) * 3 + 2] = sz[c];
    }
}

// ---------------- ball query: one wave per (b,s) ----------------
__global__ __launch_bounds__(256) void ballq_kernel(const float* __restrict__ xyz,
                                                    const float* __restrict__ new_xyz,
                                                    int* __restrict__ gi) {
    const int lane = threadIdx.x & 63;
    const int w    = threadIdx.x >> 6;
    const int pair = blockIdx.x * 4 + w;   // b*NPOINT + s
    const int b    = pair >> 10;
    const float R2 = (float)(0.4 * 0.4);
    const float* xb = xyz + (size_t)b * NPTS * 3;
    const float cx = new_xyz[pair * 3 + 0];
    const float cy = new_xyz[pair * 3 + 1];
    const float cz = new_xyz[pair * 3 + 2];
    int* g = gi + (size_t)pair * NSAMP;

    int found = 0, first = 0;
    bool have_first = false;
    for (int c0 = 0; c0 < NPTS; c0 += 64) {
        const int n = c0 + lane;
        float d = sqdist(xb[n * 3 + 0], xb[n * 3 + 1], xb[n * 3 + 2], cx, cy, cz);
        bool in = !(d > R2);
        unsigned long long m = __ballot(in);
        if (m) {
            if (!have_first) { first = c0 + (__ffsll(m) - 1); have_first = true; }
            if (in) {
                int slot = found + (int)__popcll(m & ((1ull << lane) - 1ull));
                if (slot < NSAMP) g[slot] = n;
            }
            found += (int)__popcll(m);
            if (found >= NSAMP) break;
        }
    }
    for (int slot = found + lane; slot < NSAMP; slot += 64) g[slot] = first;
}

// ---------------- P[n] = W0 * [xyz, points] + b0  (65536 rows, computed once) ----------------
__global__ __launch_bounds__(256) void point_p_kernel(
    const float* __restrict__ xyz, const float* __restrict__ points,
    const float* __restrict__ w0, const float* __restrict__ b0,
    float* __restrict__ P) {
    __shared__ __align__(16) float xw[64][68];
    __shared__ __align__(16) float wt[64][68];
    const int tid = threadIdx.x, blk = blockIdx.x;
    const int pt0 = blk * 64;
    const int ty = tid >> 4, tx = tid & 15;

    for (int idx = tid; idx < 64 * 3; idx += 256) {
        int r = idx / 3, d = idx - r * 3;
        xw[r][d] = xyz[(size_t)(pt0 + r) * 3 + d];
    }
    for (int idx = tid; idx < 64 * 64; idx += 256) {
        int r = idx >> 6, c = idx & 63;
        xw[r][3 + c] = points[(size_t)(pt0 + r) * CIN + c];
    }
    for (int idx = tid; idx < 64 * 67; idx += 256) {
        int o = idx / 67, c = idx - o * 67;
        wt[o][c] = w0[idx];
    }
    __syncthreads();

    float acc[4][4];
    {
        float bj[4];
#pragma unroll
        for (int j = 0; j < 4; ++j) bj[j] = b0[tx + 16 * j];
#pragma unroll
        for (int i = 0; i < 4; ++i)
#pragma unroll
            for (int j = 0; j < 4; ++j) acc[i][j] = bj[j];
    }
    for (int c4 = 0; c4 < 64; c4 += 4) {
        float4 xv[4], wv[4];
#pragma unroll
        for (int i = 0; i < 4; ++i) xv[i] = *(const float4*)&xw[ty + 16 * i][c4];
#pragma unroll
        for (int j = 0; j < 4; ++j) wv[j] = *(const float4*)&wt[tx + 16 * j][c4];
#pragma unroll
        for (int i = 0; i < 4; ++i)
#pragma unroll
            for (int j = 0; j < 4; ++j)
                acc[i][j] += xv[i].x * wv[j].x + xv[i].y * wv[j].y +
                             xv[i].z * wv[j].z + xv[i].w * wv[j].w;
    }
#pragma unroll
    for (int c = 64; c < 67; ++c) {
        float xv[4], wv[4];
#pragma unroll
        for (int i = 0; i < 4; ++i) xv[i] = xw[ty + 16 * i][c];
#pragma unroll
        for (int j = 0; j < 4; ++j) wv[j] = wt[tx + 16 * j][c];
#pragma unroll
        for (int i = 0; i < 4; ++i)
#pragma unroll
            for (int j = 0; j < 4; ++j) acc[i][j] += xv[i] * wv[j];
    }
#pragma unroll
    for (int i = 0; i < 4; ++i)
#pragma unroll
        for (int j = 0; j < 4; ++j)
            P[(size_t)(pt0 + ty + 16 * i) * 64 + tx + 16 * j] = acc[i][j];
}

// ---------------- Q[s] = W0xyz * new_xyz[s] (no bias) ----------------
__global__ __launch_bounds__(256) void point_q_kernel(const float* __restrict__ new_xyz,
                                                      const float* __restrict__ w0,
                                                      float* __restrict__ Q) {
    int idx = blockIdx.x * 256 + threadIdx.x;   // 16384*64
    int s = idx >> 6, o = idx & 63;
    float x = new_xyz[s * 3 + 0], y = new_xyz[s * 3 + 1], z = new_xyz[s * 3 + 2];
    Q[idx] = w0[o * 67 + 0] * x + w0[o * 67 + 1] * y + w0[o * 67 + 2] * z;
}

// ---------------- stats of raw y0 = P[n] - Q[s] ----------------
__global__ __launch_bounds__(256) void stats0_kernel(
    const float* __restrict__ P, const float* __restrict__ Q,
    const int* __restrict__ gi, float* __restrict__ partial) {
    __shared__ __align__(16) float xw[64][68];
    __shared__ int s_n[64];
    const int tid = threadIdx.x, blk = blockIdx.x;
    const int row0 = blk * 64;
    if (tid < 64) s_n[tid] = ((row0 + tid) >> 15) * NPTS + gi[row0 + tid];
    __syncthreads();
    for (int idx = tid; idx < 64 * 16; idx += 256) {
        int r = idx >> 4, c4 = idx & 15;
        float4 pv = *(const float4*)(P + ((size_t)s_n[r] << 6) + c4 * 4);
        float4 qv = *(const float4*)(Q + ((size_t)(blk * 2 + (r >> 5)) << 6) + c4 * 4);
        float4 y; y.x = pv.x - qv.x; y.y = pv.y - qv.y; y.z = pv.z - qv.z; y.w = pv.w - qv.w;
        *(float4*)&xw[r][c4 * 4] = y;
    }
    __syncthreads();
    if (tid < 64) {
        float s = 0.f, q = 0.f;
        for (int r = 0; r < 64; ++r) { float v = xw[r][tid]; s += v; q += v * v; }
        partial[(size_t)blk * 128 + tid]      = s;
        partial[(size_t)blk * 128 + 64 + tid] = q;
    }
}

// ---------------- chain1: h0 = relu(bn0(P-Q)); y1 = h0*W1+b1; stats ----------------
__global__ __launch_bounds__(256) void chain1_kernel(
    const float* __restrict__ P, const float* __restrict__ Q,
    const int* __restrict__ gi, const float* __restrict__ w1, const float* __restrict__ b1,
    const float* __restrict__ ss, float* __restrict__ partial) {
    __shared__ __align__(16) float xw[64][68];
    __shared__ __align__(16) float wt[64][68];
    __shared__ int s_n[64];
    const int tid = threadIdx.x, blk = blockIdx.x;
    const int row0 = blk * 64;
    const int ty = tid >> 4, tx = tid & 15;

    if (tid < 64) s_n[tid] = ((row0 + tid) >> 15) * NPTS + gi[row0 + tid];
    for (int idx = tid; idx < 64 * 64; idx += 256) {
        int o = idx >> 6, c = idx & 63;
        wt[o][c] = w1[idx];
    }
    __syncthreads();
    for (int idx = tid; idx < 64 * 16; idx += 256) {
        int r = idx >> 4, c4 = idx & 15, c = c4 * 4;
        float4 pv = *(const float4*)(P + ((size_t)s_n[r] << 6) + c);
        float4 qv = *(const float4*)(Q + ((size_t)(blk * 2 + (r >> 5)) << 6) + c);
        float4 y;
        y.x = fmaxf((pv.x - qv.x) * ss[c + 0] + ss[128 + c + 0], 0.f);
        y.y = fmaxf((pv.y - qv.y) * ss[c + 1] + ss[128 + c + 1], 0.f);
        y.z = fmaxf((pv.z - qv.z) * ss[c + 2] + ss[128 + c + 2], 0.f);
        y.w = fmaxf((pv.w - qv.w) * ss[c + 3] + ss[128 + c + 3], 0.f);
        *(float4*)&xw[r][c] = y;
    }
    __syncthreads();

    float acc[4][4];
    {
        float bj[4];
#pragma unroll
        for (int j = 0; j < 4; ++j) bj[j] = b1[tx + 16 * j];
#pragma unroll
        for (int i = 0; i < 4; ++i)
#pragma unroll
            for (int j = 0; j < 4; ++j) acc[i][j] = bj[j];
    }
    for (int c4 = 0; c4 < 64; c4 += 4) {
        float4 xv[4], wv[4];
#pragma unroll
        for (int i = 0; i < 4; ++i) xv[i] = *(const float4*)&xw[ty + 16 * i][c4];
#pragma unroll
        for (int j = 0; j < 4; ++j) wv[j] = *(const float4*)&wt[tx + 16 * j][c4];
#pragma unroll
        for (int i = 0; i < 4; ++i)
#pragma unroll
            for (int j = 0; j < 4; ++j)
                acc[i][j] += xv[i].x * wv[j].x + xv[i].y * wv[j].y +
                             xv[i].z * wv[j].z + xv[i].w * wv[j].w;
    }
    __syncthreads();
#pragma unroll
    for (int i = 0; i < 4; ++i)
#pragma unroll
        for (int j = 0; j < 4; ++j) xw[ty + 16 * i][tx + 16 * j] = acc[i][j];
    __syncthreads();
    if (tid < 64) {
        float s = 0.f, q = 0.f;
        for (int r = 0; r < 64; ++r) { float v = xw[r][tid]; s += v; q += v * v; }
        partial[(size_t)blk * 128 + tid]      = s;
        partial[(size_t)blk * 128 + 64 + tid] = q;
    }
}

// ---------------- chain2: ...bn1+relu; y2 = h1*W2+b2; stats2 + maxpool ----------------
__global__ __launch_bounds__(256) void chain2_kernel(
    const float* __restrict__ P, const float* __restrict__ Q,
    const int* __restrict__ gi,
    const float* __restrict__ w1, const float* __restrict__ b1,
    const float* __restrict__ w2, const float* __restrict__ b2,
    const float* __restrict__ ss, float* __restrict__ partial,
    float* __restrict__ maxy) {
    __shared__ __align__(16) float xw[64][68];
    __shared__ __align__(16) float wt[128][68];
    __shared__ int s_n[64];
    const int tid = threadIdx.x, blk = blockIdx.x;
    const int row0 = blk * 64;
    const int ty = tid >> 4, tx = tid & 15;

    if (tid < 64) s_n[tid] = ((row0 + tid) >> 15) * NPTS + gi[row0 + tid];
    for (int idx = tid; idx < 64 * 64; idx += 256) {
        int o = idx >> 6, c = idx & 63;
        wt[o][c] = w1[idx];
    }
    __syncthreads();
    for (int idx = tid; idx < 64 * 16; idx += 256) {
        int r = idx >> 4, c4 = idx & 15, c = c4 * 4;
        float4 pv = *(const float4*)(P + ((size_t)s_n[r] << 6) + c);
        float4 qv = *(const float4*)(Q + ((size_t)(blk * 2 + (r >> 5)) << 6) + c);
        float4 y;
        y.x = fmaxf((pv.x - qv.x) * ss[c + 0] + ss[128 + c + 0], 0.f);
        y.y = fmaxf((pv.y - qv.y) * ss[c + 1] + ss[128 + c + 1], 0.f);
        y.z = fmaxf((pv.z - qv.z) * ss[c + 2] + ss[128 + c + 2], 0.f);
        y.w = fmaxf((pv.w - qv.w) * ss[c + 3] + ss[128 + c + 3], 0.f);
        *(float4*)&xw[r][c] = y;
    }
    __syncthreads();

    float acc[4][4];
    {
        float bj[4];
#pragma unroll
        for (int j = 0; j < 4; ++j) bj[j] = b1[tx + 16 * j];
#pragma unroll
        for (int i = 0; i < 4; ++i)
#pragma unroll
            for (int j = 0; j < 4; ++j) acc[i][j] = bj[j];
    }
    for (int c4 = 0; c4 < 64; c4 += 4) {
        float4 xv[4], wv[4];
#pragma unroll
        for (int i = 0; i < 4; ++i) xv[i] = *(const float4*)&xw[ty + 16 * i][c4];
#pragma unroll
        for (int j = 0; j < 4; ++j) wv[j] = *(const float4*)&wt[tx + 16 * j][c4];
#pragma unroll
        for (int i = 0; i < 4; ++i)
#pragma unroll
            for (int j = 0; j < 4; ++j)
                acc[i][j] += xv[i].x * wv[j].x + xv[i].y * wv[j].y +
                             xv[i].z * wv[j].z + xv[i].w * wv[j].w;
    }
    __syncthreads();
#pragma unroll
    for (int i = 0; i < 4; ++i)
#pragma unroll
        for (int j = 0; j < 4; ++j) {
            int o = tx + 16 * j;
            xw[ty + 16 * i][o] = fmaxf(acc[i][j] * ss[256 + o] + ss[384 + o], 0.f);
        }
    for (int idx = tid; idx < 128 * 64; idx += 256) {
        int o = idx >> 6, c = idx & 63;
        wt[o][c] = w2[idx];
    }
    __syncthreads();

    float acc2[4][8];
    {
        float bj[8];
#pragma unroll
        for (int j = 0; j < 8; ++j) bj[j] = b2[tx + 16 * j];
#pragma unroll
        for (int i = 0; i < 4; ++i)
#pragma unroll
            for (int j = 0; j < 8; ++j) acc2[i][j] = bj[j];
    }
    for (int c4 = 0; c4 < 64; c4 += 4) {
        float4 xv[4], wv[8];
#pragma unroll
        for (int i = 0; i < 4; ++i) xv[i] = *(const float4*)&xw[ty + 16 * i][c4];
#pragma unroll
        for (int j = 0; j < 8; ++j) wv[j] = *(const float4*)&wt[tx + 16 * j][c4];
#pragma unroll
        for (int i = 0; i < 4; ++i)
#pragma unroll
            for (int j = 0; j < 8; ++j)
                acc2[i][j] += xv[i].x * wv[j].x + xv[i].y * wv[j].y +
                              xv[i].z * wv[j].z + xv[i].w * wv[j].w;
    }

    const int bs0 = blk * 2;
#pragma unroll
    for (int half = 0; half < 2; ++half) {
        __syncthreads();
#pragma unroll
        for (int i = 0; i < 4; ++i)
#pragma unroll
            for (int jj = 0; jj < 4; ++jj)
                xw[ty + 16 * i][tx + 16 * jj] = acc2[i][half * 4 + jj];
        __syncthreads();
        if (tid < 64) {
            float s = 0.f, q = 0.f, m0 = -1e30f, m1 = -1e30f;
            for (int r = 0; r < 32; ++r)  { float v = xw[r][tid]; s += v; q += v * v; m0 = fmaxf(m0, v); }
            for (int r = 32; r < 64; ++r) { float v = xw[r][tid]; s += v; q += v * v; m1 = fmaxf(m1, v); }
            int cg = half * 64 + tid;
            partial[(size_t)blk * 256 + cg]       = s;
            partial[(size_t)blk * 256 + 128 + cg] = q;
            maxy[(size_t)bs0 * 128 + cg]          = m0;
            maxy[(size_t)(bs0 + 1) * 128 + cg]    = m1;
        }
    }
}

// ---------------- reduce stats -> scale/shift ----------------
__global__ __launch_bounds__(256) void reduce_stats_kernel(
    const float* __restrict__ partial, int Cd, float inv_count,
    const float* __restrict__ g, const float* __restrict__ be,
    float* __restrict__ ss_layer) {
    const int c   = blockIdx.x;
    const int tid = threadIdx.x;
    float s = 0.f, q = 0.f;
    for (int blk = tid; blk < NBLK; blk += 256) {
        s += partial[(size_t)blk * 2 * Cd + c];
        q += partial[(size_t)blk * 2 * Cd + Cd + c];
    }
#pragma unroll
    for (int m = 1; m < 64; m <<= 1) { s += __shfl_xor(s, m); q += __shfl_xor(q, m); }
    __shared__ float ls[4], lq[4];
    const int wid = tid >> 6;
    if ((tid & 63) == 0) { ls[wid] = s; lq[wid] = q; }
    __syncthreads();
    if (tid == 0) {
        s = ls[0] + ls[1] + ls[2] + ls[3];
        q = lq[0] + lq[1] + lq[2] + lq[3];
        float mean = s * inv_count;
        float var  = q * inv_count - mean * mean;
        float sc   = g[c] / sqrtf(var + 1e-5f);
        ss_layer[c]       = sc;
        ss_layer[128 + c] = be[c] - mean * sc;
    }
}

// ---------------- final: BN2 + ReLU applied to max-pooled y2 ----------------
__global__ __launch_bounds__(256) void final_kernel(const float* __restrict__ maxy,
                                                    const float* __restrict__ ss2,
                                                    float* __restrict__ outp) {
    int idx = blockIdx.x * 256 + threadIdx.x;
    int c = idx & 127;
    float v = maxy[idx] * ss2[c] + ss2[128 + c];
    outp[idx] = fmaxf(v, 0.f);
}

extern "C" void kernel_launch(void* const* d_in, const int* in_sizes, int n_in,
                              void* d_out, int out_size, void* d_ws, size_t ws_size,
                              hipStream_t stream) {
    const float* xyz    = (const float*)d_in[0];
    const float* points = (const float*)d_in[1];
    const float* w0 = (const float*)d_in[2];  const float* b0  = (const float*)d_in[3];
    const float* g0 = (const float*)d_in[4];  const float* be0 = (const float*)d_in[5];
    const float* w1 = (const float*)d_in[6];  const float* b1  = (const float*)d_in[7];
    const float* g1 = (const float*)d_in[8];  const float* be1 = (const float*)d_in[9];
    const float* w2 = (const float*)d_in[10]; const float* b2  = (const float*)d_in[11];
    const float* g2 = (const float*)d_in[12]; const float* be2 = (const float*)d_in[13];

    float* out      = (float*)d_out;
    float* new_xyz  = out;                                 // [B, S, 3]
    float* out_pts  = out + (size_t)BATCH * NPOINT * 3;    // [B, S, 128]

    char* p = (char*)d_ws;
    int* gi = (int*)p;          p += (((size_t)ROWS * 4) + 255) & ~(size_t)255;
    float* partial = (float*)p; p += (((size_t)NBLK * 256 * 4) + 255) & ~(size_t)255;
    float* ss = (float*)p;      p += ((size_t)(3 * 256 * 4) + 255) & ~(size_t)255;
    float* maxy = (float*)p;    p += (((size_t)BATCH * NPOINT * 128 * 4) + 255) & ~(size_t)255;
    float* P = (float*)p;       p += (((size_t)BATCH * NPTS * 64 * 4) + 255) & ~(size_t)255;
    float* Q = (float*)p;       // [B*NPOINT][64]

    const float inv_count = 1.0f / (float)ROWS;

    fps_kernel<<<BATCH, 1024, 0, stream>>>(xyz, new_xyz);
    ballq_kernel<<<(BATCH * NPOINT) / 4, 256, 0, stream>>>(xyz, new_xyz, gi);
    point_p_kernel<<<(BATCH * NPTS) / 64, 256, 0, stream>>>(xyz, points, w0, b0, P);
    point_q_kernel<<<(BATCH * NPOINT * 64) / 256, 256, 0, stream>>>(new_xyz, w0, Q);

    stats0_kernel<<<NBLK, 256, 0, stream>>>(P, Q, gi, partial);
    reduce_stats_kernel<<<64, 256, 0, stream>>>(partial, 64, inv_count, g0, be0, ss + 0);

    chain1_kernel<<<NBLK, 256, 0, stream>>>(P, Q, gi, w1, b1, ss, partial);
    reduce_stats_kernel<<<64, 256, 0, stream>>>(partial, 64, inv_count, g1, be1, ss + 256);

    chain2_kernel<<<NBLK, 256, 0, stream>>>(P, Q, gi, w1, b1, w2, b2, ss, partial, maxy);
    reduce_stats_kernel<<<128, 256, 0, stream>>>(partial, 128, inv_count, g2, be2, ss + 512);

    final_kernel<<<(BATCH * NPOINT * 128) / 256, 256, 0, stream>>>(maxy, ss + 512, out_pts);
}

// Round 3
// 1072.607 us; speedup vs baseline: 2.0459x; 1.5090x over previous
//
#include <hip/hip_runtime.h>
#include <math.h>

// PointNet++ SA: FPS -> ball query -> gather -> 3x(1x1conv+BN+ReLU) -> maxpool(K)
// R2: FPS v3 (DPP wave-max, 512thr/8pts, 8-entry cross-wave scan) fused with P GEMM.

static constexpr int BATCH  = 16;
static constexpr int NPTS   = 4096;
static constexpr int NPOINT = 1024;
static constexpr int NSAMP  = 32;
static constexpr int CIN    = 64;
static constexpr int ROWS   = BATCH * NPOINT * NSAMP;  // 524288
static constexpr int NBLK   = ROWS / 64;               // 8192

typedef unsigned long long u64;

__device__ __forceinline__ float sqdist(float x, float y, float z,
                                        float cx, float cy, float cz) {
    // exact IEEE order: (dx*dx + dy*dy) + dz*dz, no fma contraction (matches reference f32)
    float dx = x - cx, dy = y - cy, dz = z - cz;
    return __fadd_rn(__fadd_rn(__fmul_rn(dx, dx), __fmul_rn(dy, dy)), __fmul_rn(dz, dz));
}

#if __has_builtin(__builtin_amdgcn_update_dpp) && __has_builtin(__builtin_amdgcn_readlane)
#define DPP_MAX(x, ctrl)                                                              \
    do {                                                                              \
        int _o = __builtin_amdgcn_update_dpp(__float_as_int(x), __float_as_int(x),    \
                                             (ctrl), 0xf, 0xf, false);                \
        (x) = fmaxf((x), __int_as_float(_o));                                         \
    } while (0)
__device__ __forceinline__ float wave_max_f32(float v) {
    DPP_MAX(v, 0x111);  // row_shr:1
    DPP_MAX(v, 0x112);  // row_shr:2
    DPP_MAX(v, 0x114);  // row_shr:4
    DPP_MAX(v, 0x118);  // row_shr:8  -> lane15 of each row has row max
    DPP_MAX(v, 0x142);  // row_bcast:15
    DPP_MAX(v, 0x143);  // row_bcast:31 -> lane 63 has wave max
    return __int_as_float(__builtin_amdgcn_readlane(__float_as_int(v), 63));
}
#else
__device__ __forceinline__ float wave_max_f32(float v) {
#pragma unroll
    for (int m = 1; m < 64; m <<= 1) v = fmaxf(v, __shfl_xor(v, m));
    return v;
}
#endif

// ---------------- fused: blocks [0,16) = FPS per batch; [16,528) = P GEMM tiles ----
__global__ __launch_bounds__(512) void pre_kernel(
    const float* __restrict__ xyz, const float* __restrict__ points,
    const float* __restrict__ w0, const float* __restrict__ b0,
    float* __restrict__ P, float* __restrict__ new_xyz) {
    __shared__ __align__(16) char s_raw[53376];
    const int tid = threadIdx.x;

    if (blockIdx.x < 16) {
        // ================= FPS role =================
        float2* sxy  = (float2*)s_raw;               // 32768 B
        float*  szv  = (float*)(s_raw + 32768);      // 16384 B
        int*    s_cent = (int*)(s_raw + 49152);      //  4096 B
        u64*    s_red  = (u64*)(s_raw + 53248);      //   128 B (2 bufs x 8)

        const int b = blockIdx.x;
        const float* xb = xyz + (size_t)b * NPTS * 3;
        for (int p = tid; p < NPTS; p += 512) {
            sxy[p] = make_float2(xb[p * 3 + 0], xb[p * 3 + 1]);
            szv[p] = xb[p * 3 + 2];
        }
        __syncthreads();
        float px[8], py[8], pz[8], dist[8];
#pragma unroll
        for (int j = 0; j < 8; ++j) {
            int p = tid + j * 512;
            float2 f = sxy[p];
            px[j] = f.x; py[j] = f.y; pz[j] = szv[p];
            dist[j] = 1e10f;
        }
        const int lane = tid & 63, wid = tid >> 6;
        int far = 0;
        for (int it = 0; it < NPOINT; ++it) {
            if (tid == 0) s_cent[it] = far;
            const float2 cxy = sxy[far];
            const float  cz  = szv[far];
            float bv = -1.0f;
            int   bi = 0;
#pragma unroll
            for (int j = 0; j < 8; ++j) {
                float d  = sqdist(px[j], py[j], pz[j], cxy.x, cxy.y, cz);
                float nd = fminf(dist[j], d);   // jnp.minimum
                dist[j]  = nd;
                if (nd > bv) { bv = nd; bi = tid + j * 512; }  // j asc -> smallest idx on tie
            }
            float gmax = wave_max_f32(bv);
            u64 mask = __ballot(bv == gmax);
            int widx = __shfl(bi, (int)__builtin_ctzll(mask));
            if (lane == 0)
                s_red[(it & 1) * 8 + wid] =
                    ((u64)__float_as_uint(gmax) << 32) | (unsigned)(4095 - widx);
            __syncthreads();
            const u64* sr = &s_red[(it & 1) * 8];
            u64 w = sr[0];
#pragma unroll
            for (int k = 1; k < 8; ++k) { u64 o = sr[k]; w = (o > w) ? o : w; }
            far = 4095 - (int)(w & 0xffffffffu);
        }
        __syncthreads();
        for (int s = tid; s < NPOINT; s += 512) {
            int c = s_cent[s];
            float2 f = sxy[c];
            new_xyz[((size_t)b * NPOINT + s) * 3 + 0] = f.x;
            new_xyz[((size_t)b * NPOINT + s) * 3 + 1] = f.y;
            new_xyz[((size_t)b * NPOINT + s) * 3 + 2] = szv[c];
        }
    } else {
        // ================= P role: P[n] = W0*[xyz,points]+b0, 128-pt tile =========
        float (*xw)[68] = (float(*)[68])s_raw;             // 34816 B
        float (*wt)[68] = (float(*)[68])(s_raw + 34816);   // 17408 B
        const int blk = blockIdx.x - 16;
        const int pt0 = blk * 128;
        const int ty = tid >> 4, tx = tid & 15;

        for (int idx = tid; idx < 128 * 3; idx += 512) {
            int r = idx / 3, d = idx - r * 3;
            xw[r][d] = xyz[(size_t)(pt0 + r) * 3 + d];
        }
        for (int idx = tid; idx < 128 * 16; idx += 512) {
            int r = idx >> 4, c4 = idx & 15;
            float4 v = *(const float4*)(points + (size_t)(pt0 + r) * CIN + c4 * 4);
            xw[r][3 + c4 * 4 + 0] = v.x;
            xw[r][3 + c4 * 4 + 1] = v.y;
            xw[r][3 + c4 * 4 + 2] = v.z;
            xw[r][3 + c4 * 4 + 3] = v.w;
        }
        for (int idx = tid; idx < 64 * 67; idx += 512) {
            int o = idx / 67, c = idx - o * 67;
            wt[o][c] = w0[idx];
        }
        __syncthreads();

        float acc[4][4];
        {
            float bj[4];
#pragma unroll
            for (int j = 0; j < 4; ++j) bj[j] = b0[tx + 16 * j];
#pragma unroll
            for (int i = 0; i < 4; ++i)
#pragma unroll
                for (int j = 0; j < 4; ++j) acc[i][j] = bj[j];
        }
        for (int c4 = 0; c4 < 64; c4 += 4) {
            float4 xv[4], wv[4];
#pragma unroll
            for (int i = 0; i < 4; ++i) xv[i] = *(const float4*)&xw[ty + 32 * i][c4];
#pragma unroll
            for (int j = 0; j < 4; ++j) wv[j] = *(const float4*)&wt[tx + 16 * j][c4];
#pragma unroll
            for (int i = 0; i < 4; ++i)
#pragma unroll
                for (int j = 0; j < 4; ++j)
                    acc[i][j] += xv[i].x * wv[j].x + xv[i].y * wv[j].y +
                                 xv[i].z * wv[j].z + xv[i].w * wv[j].w;
        }
#pragma unroll
        for (int c = 64; c < 67; ++c) {
            float xv[4], wv[4];
#pragma unroll
            for (int i = 0; i < 4; ++i) xv[i] = xw[ty + 32 * i][c];
#pragma unroll
            for (int j = 0; j < 4; ++j) wv[j] = wt[tx + 16 * j][c];
#pragma unroll
            for (int i = 0; i < 4; ++i)
#pragma unroll
                for (int j = 0; j < 4; ++j) acc[i][j] += xv[i] * wv[j];
        }
#pragma unroll
        for (int i = 0; i < 4; ++i)
#pragma unroll
            for (int j = 0; j < 4; ++j)
                P[(size_t)(pt0 + ty + 32 * i) * 64 + tx + 16 * j] = acc[i][j];
    }
}

// ---------------- ball query: one wave per (b,s) ----------------
__global__ __launch_bounds__(256) void ballq_kernel(const float* __restrict__ xyz,
                                                    const float* __restrict__ new_xyz,
                                                    int* __restrict__ gi) {
    const int lane = threadIdx.x & 63;
    const int w    = threadIdx.x >> 6;
    const int pair = blockIdx.x * 4 + w;   // b*NPOINT + s
    const int b    = pair >> 10;
    const float R2 = (float)(0.4 * 0.4);
    const float* xb = xyz + (size_t)b * NPTS * 3;
    const float cx = new_xyz[pair * 3 + 0];
    const float cy = new_xyz[pair * 3 + 1];
    const float cz = new_xyz[pair * 3 + 2];
    int* g = gi + (size_t)pair * NSAMP;

    int found = 0, first = 0;
    bool have_first = false;
    for (int c0 = 0; c0 < NPTS; c0 += 64) {
        const int n = c0 + lane;
        float d = sqdist(xb[n * 3 + 0], xb[n * 3 + 1], xb[n * 3 + 2], cx, cy, cz);
        bool in = !(d > R2);
        unsigned long long m = __ballot(in);
        if (m) {
            if (!have_first) { first = c0 + (__ffsll(m) - 1); have_first = true; }
            if (in) {
                int slot = found + (int)__popcll(m & ((1ull << lane) - 1ull));
                if (slot < NSAMP) g[slot] = n;
            }
            found += (int)__popcll(m);
            if (found >= NSAMP) break;
        }
    }
    for (int slot = found + lane; slot < NSAMP; slot += 64) g[slot] = first;
}

// ---------------- Q[s] = W0xyz * new_xyz[s] (no bias) ----------------
__global__ __launch_bounds__(256) void point_q_kernel(const float* __restrict__ new_xyz,
                                                      const float* __restrict__ w0,
                                                      float* __restrict__ Q) {
    int idx = blockIdx.x * 256 + threadIdx.x;   // 16384*64
    int s = idx >> 6, o = idx & 63;
    float x = new_xyz[s * 3 + 0], y = new_xyz[s * 3 + 1], z = new_xyz[s * 3 + 2];
    Q[idx] = w0[o * 67 + 0] * x + w0[o * 67 + 1] * y + w0[o * 67 + 2] * z;
}

// ---------------- stats of raw y0 = P[n] - Q[s] ----------------
__global__ __launch_bounds__(256) void stats0_kernel(
    const float* __restrict__ P, const float* __restrict__ Q,
    const int* __restrict__ gi, float* __restrict__ partial) {
    __shared__ __align__(16) float xw[64][68];
    __shared__ int s_n[64];
    const int tid = threadIdx.x, blk = blockIdx.x;
    const int row0 = blk * 64;
    if (tid < 64) s_n[tid] = ((row0 + tid) >> 15) * NPTS + gi[row0 + tid];
    __syncthreads();
    for (int idx = tid; idx < 64 * 16; idx += 256) {
        int r = idx >> 4, c4 = idx & 15;
        float4 pv = *(const float4*)(P + ((size_t)s_n[r] << 6) + c4 * 4);
        float4 qv = *(const float4*)(Q + ((size_t)(blk * 2 + (r >> 5)) << 6) + c4 * 4);
        float4 y; y.x = pv.x - qv.x; y.y = pv.y - qv.y; y.z = pv.z - qv.z; y.w = pv.w - qv.w;
        *(float4*)&xw[r][c4 * 4] = y;
    }
    __syncthreads();
    if (tid < 64) {
        float s = 0.f, q = 0.f;
        for (int r = 0; r < 64; ++r) { float v = xw[r][tid]; s += v; q += v * v; }
        partial[(size_t)blk * 128 + tid]      = s;
        partial[(size_t)blk * 128 + 64 + tid] = q;
    }
}

// ---------------- chain1: h0 = relu(bn0(P-Q)); y1 = h0*W1+b1; stats ----------------
__global__ __launch_bounds__(256) void chain1_kernel(
    const float* __restrict__ P, const float* __restrict__ Q,
    const int* __restrict__ gi, const float* __restrict__ w1, const float* __restrict__ b1,
    const float* __restrict__ ss, float* __restrict__ partial) {
    __shared__ __align__(16) float xw[64][68];
    __shared__ __align__(16) float wt[64][68];
    __shared__ int s_n[64];
    const int tid = threadIdx.x, blk = blockIdx.x;
    const int row0 = blk * 64;
    const int ty = tid >> 4, tx = tid & 15;

    if (tid < 64) s_n[tid] = ((row0 + tid) >> 15) * NPTS + gi[row0 + tid];
    for (int idx = tid; idx < 64 * 64; idx += 256) {
        int o = idx >> 6, c = idx & 63;
        wt[o][c] = w1[idx];
    }
    __syncthreads();
    for (int idx = tid; idx < 64 * 16; idx += 256) {
        int r = idx >> 4, c4 = idx & 15, c = c4 * 4;
        float4 pv = *(const float4*)(P + ((size_t)s_n[r] << 6) + c);
        float4 qv = *(const float4*)(Q + ((size_t)(blk * 2 + (r >> 5)) << 6) + c);
        float4 y;
        y.x = fmaxf((pv.x - qv.x) * ss[c + 0] + ss[128 + c + 0], 0.f);
        y.y = fmaxf((pv.y - qv.y) * ss[c + 1] + ss[128 + c + 1], 0.f);
        y.z = fmaxf((pv.z - qv.z) * ss[c + 2] + ss[128 + c + 2], 0.f);
        y.w = fmaxf((pv.w - qv.w) * ss[c + 3] + ss[128 + c + 3], 0.f);
        *(float4*)&xw[r][c] = y;
    }
    __syncthreads();

    float acc[4][4];
    {
        float bj[4];
#pragma unroll
        for (int j = 0; j < 4; ++j) bj[j] = b1[tx + 16 * j];
#pragma unroll
        for (int i = 0; i < 4; ++i)
#pragma unroll
            for (int j = 0; j < 4; ++j) acc[i][j] = bj[j];
    }
    for (int c4 = 0; c4 < 64; c4 += 4) {
        float4 xv[4], wv[4];
#pragma unroll
        for (int i = 0; i < 4; ++i) xv[i] = *(const float4*)&xw[ty + 16 * i][c4];
#pragma unroll
        for (int j = 0; j < 4; ++j) wv[j] = *(const float4*)&wt[tx + 16 * j][c4];
#pragma unroll
        for (int i = 0; i < 4; ++i)
#pragma unroll
            for (int j = 0; j < 4; ++j)
                acc[i][j] += xv[i].x * wv[j].x + xv[i].y * wv[j].y +
                             xv[i].z * wv[j].z + xv[i].w * wv[j].w;
    }
    __syncthreads();
#pragma unroll
    for (int i = 0; i < 4; ++i)
#pragma unroll
        for (int j = 0; j < 4; ++j) xw[ty + 16 * i][tx + 16 * j] = acc[i][j];
    __syncthreads();
    if (tid < 64) {
        float s = 0.f, q = 0.f;
        for (int r = 0; r < 64; ++r) { float v = xw[r][tid]; s += v; q += v * v; }
        partial[(size_t)blk * 128 + tid]      = s;
        partial[(size_t)blk * 128 + 64 + tid] = q;
    }
}

// ---------------- chain2: ...bn1+relu; y2 = h1*W2+b2; stats2 + maxpool ----------------
__global__ __launch_bounds__(256) void chain2_kernel(
    const float* __restrict__ P, const float* __restrict__ Q,
    const int* __restrict__ gi,
    const float* __restrict__ w1, const float* __restrict__ b1,
    const float* __restrict__ w2, const float* __restrict__ b2,
    const float* __restrict__ ss, float* __restrict__ partial,
    float* __restrict__ maxy) {
    __shared__ __align__(16) float xw[64][68];
    __shared__ __align__(16) float wt[128][68];
    __shared__ int s_n[64];
    const int tid = threadIdx.x, blk = blockIdx.x;
    const int row0 = blk * 64;
    const int ty = tid >> 4, tx = tid & 15;

    if (tid < 64) s_n[tid] = ((row0 + tid) >> 15) * NPTS + gi[row0 + tid];
    for (int idx = tid; idx < 64 * 64; idx += 256) {
        int o = idx >> 6, c = idx & 63;
        wt[o][c] = w1[idx];
    }
    __syncthreads();
    for (int idx = tid; idx < 64 * 16; idx += 256) {
        int r = idx >> 4, c4 = idx & 15, c = c4 * 4;
        float4 pv = *(const float4*)(P + ((size_t)s_n[r] << 6) + c);
        float4 qv = *(const float4*)(Q + ((size_t)(blk * 2 + (r >> 5)) << 6) + c);
        float4 y;
        y.x = fmaxf((pv.x - qv.x) * ss[c + 0] + ss[128 + c + 0], 0.f);
        y.y = fmaxf((pv.y - qv.y) * ss[c + 1] + ss[128 + c + 1], 0.f);
        y.z = fmaxf((pv.z - qv.z) * ss[c + 2] + ss[128 + c + 2], 0.f);
        y.w = fmaxf((pv.w - qv.w) * ss[c + 3] + ss[128 + c + 3], 0.f);
        *(float4*)&xw[r][c] = y;
    }
    __syncthreads();

    float acc[4][4];
    {
        float bj[4];
#pragma unroll
        for (int j = 0; j < 4; ++j) bj[j] = b1[tx + 16 * j];
#pragma unroll
        for (int i = 0; i < 4; ++i)
#pragma unroll
            for (int j = 0; j < 4; ++j) acc[i][j] = bj[j];
    }
    for (int c4 = 0; c4 < 64; c4 += 4) {
        float4 xv[4], wv[4];
#pragma unroll
        for (int i = 0; i < 4; ++i) xv[i] = *(const float4*)&xw[ty + 16 * i][c4];
#pragma unroll
        for (int j = 0; j < 4; ++j) wv[j] = *(const float4*)&wt[tx + 16 * j][c4];
#pragma unroll
        for (int i = 0; i < 4; ++i)
#pragma unroll
            for (int j = 0; j < 4; ++j)
                acc[i][j] += xv[i].x * wv[j].x + xv[i].y * wv[j].y +
                             xv[i].z * wv[j].z + xv[i].w * wv[j].w;
    }
    __syncthreads();
#pragma unroll
    for (int i = 0; i < 4; ++i)
#pragma unroll
        for (int j = 0; j < 4; ++j) {
            int o = tx + 16 * j;
            xw[ty + 16 * i][o] = fmaxf(acc[i][j] * ss[256 + o] + ss[384 + o], 0.f);
        }
    for (int idx = tid; idx < 128 * 64; idx += 256) {
        int o = idx >> 6, c = idx & 63;
        wt[o][c] = w2[idx];
    }
    __syncthreads();

    float acc2[4][8];
    {
        float bj[8];
#pragma unroll
        for (int j = 0; j < 8; ++j) bj[j] = b2[tx + 16 * j];
#pragma unroll
        for (int i = 0; i < 4; ++i)
#pragma unroll
            for (int j = 0; j < 8; ++j) acc2[i][j] = bj[j];
    }
    for (int c4 = 0; c4 < 64; c4 += 4) {
        float4 xv[4], wv[8];
#pragma unroll
        for (int i = 0; i < 4; ++i) xv[i] = *(const float4*)&xw[ty + 16 * i][c4];
#pragma unroll
        for (int j = 0; j < 8; ++j) wv[j] = *(const float4*)&wt[tx + 16 * j][c4];
#pragma unroll
        for (int i = 0; i < 4; ++i)
#pragma unroll
            for (int j = 0; j < 8; ++j)
                acc2[i][j] += xv[i].x * wv[j].x + xv[i].y * wv[j].y +
                              xv[i].z * wv[j].z + xv[i].w * wv[j].w;
    }

    const int bs0 = blk * 2;
#pragma unroll
    for (int half = 0; half < 2; ++half) {
        __syncthreads();
#pragma unroll
        for (int i = 0; i < 4; ++i)
#pragma unroll
            for (int jj = 0; jj < 4; ++jj)
                xw[ty + 16 * i][tx + 16 * jj] = acc2[i][half * 4 + jj];
        __syncthreads();
        if (tid < 64) {
            float s = 0.f, q = 0.f, m0 = -1e30f, m1 = -1e30f;
            for (int r = 0; r < 32; ++r)  { float v = xw[r][tid]; s += v; q += v * v; m0 = fmaxf(m0, v); }
            for (int r = 32; r < 64; ++r) { float v = xw[r][tid]; s += v; q += v * v; m1 = fmaxf(m1, v); }
            int cg = half * 64 + tid;
            partial[(size_t)blk * 256 + cg]       = s;
            partial[(size_t)blk * 256 + 128 + cg] = q;
            maxy[(size_t)bs0 * 128 + cg]          = m0;
            maxy[(size_t)(bs0 + 1) * 128 + cg]    = m1;
        }
    }
}

// ---------------- reduce stats -> scale/shift ----------------
__global__ __launch_bounds__(256) void reduce_stats_kernel(
    const float* __restrict__ partial, int Cd, float inv_count,
    const float* __restrict__ g, const float* __restrict__ be,
    float* __restrict__ ss_layer) {
    const int c   = blockIdx.x;
    const int tid = threadIdx.x;
    float s = 0.f, q = 0.f;
    for (int blk = tid; blk < NBLK; blk += 256) {
        s += partial[(size_t)blk * 2 * Cd + c];
        q += partial[(size_t)blk * 2 * Cd + Cd + c];
    }
#pragma unroll
    for (int m = 1; m < 64; m <<= 1) { s += __shfl_xor(s, m); q += __shfl_xor(q, m); }
    __shared__ float ls[4], lq[4];
    const int wid = tid >> 6;
    if ((tid & 63) == 0) { ls[wid] = s; lq[wid] = q; }
    __syncthreads();
    if (tid == 0) {
        s = ls[0] + ls[1] + ls[2] + ls[3];
        q = lq[0] + lq[1] + lq[2] + lq[3];
        float mean = s * inv_count;
        float var  = q * inv_count - mean * mean;
        float sc   = g[c] / sqrtf(var + 1e-5f);
        ss_layer[c]       = sc;
        ss_layer[128 + c] = be[c] - mean * sc;
    }
}

// ---------------- final: BN2 + ReLU applied to max-pooled y2 ----------------
__global__ __launch_bounds__(256) void final_kernel(const float* __restrict__ maxy,
                                                    const float* __restrict__ ss2,
                                                    float* __restrict__ outp) {
    int idx = blockIdx.x * 256 + threadIdx.x;
    int c = idx & 127;
    float v = maxy[idx] * ss2[c] + ss2[128 + c];
    outp[idx] = fmaxf(v, 0.f);
}

extern "C" void kernel_launch(void* const* d_in, const int* in_sizes, int n_in,
                              void* d_out, int out_size, void* d_ws, size_t ws_size,
                              hipStream_t stream) {
    const float* xyz    = (const float*)d_in[0];
    const float* points = (const float*)d_in[1];
    const float* w0 = (const float*)d_in[2];  const float* b0  = (const float*)d_in[3];
    const float* g0 = (const float*)d_in[4];  const float* be0 = (const float*)d_in[5];
    const float* w1 = (const float*)d_in[6];  const float* b1  = (const float*)d_in[7];
    const float* g1 = (const float*)d_in[8];  const float* be1 = (const float*)d_in[9];
    const float* w2 = (const float*)d_in[10]; const float* b2  = (const float*)d_in[11];
    const float* g2 = (const float*)d_in[12]; const float* be2 = (const float*)d_in[13];

    float* out      = (float*)d_out;
    float* new_xyz  = out;                                 // [B, S, 3]
    float* out_pts  = out + (size_t)BATCH * NPOINT * 3;    // [B, S, 128]

    char* p = (char*)d_ws;
    int* gi = (int*)p;          p += (((size_t)ROWS * 4) + 255) & ~(size_t)255;
    float* partial = (float*)p; p += (((size_t)NBLK * 256 * 4) + 255) & ~(size_t)255;
    float* ss = (float*)p;      p += ((size_t)(3 * 256 * 4) + 255) & ~(size_t)255;
    float* maxy = (float*)p;    p += (((size_t)BATCH * NPOINT * 128 * 4) + 255) & ~(size_t)255;
    float* P = (float*)p;       p += (((size_t)BATCH * NPTS * 64 * 4) + 255) & ~(size_t)255;
    float* Q = (float*)p;       // [B*NPOINT][64]

    const float inv_count = 1.0f / (float)ROWS;

    pre_kernel<<<16 + 512, 512, 0, stream>>>(xyz, points, w0, b0, P, new_xyz);
    ballq_kernel<<<(BATCH * NPOINT) / 4, 256, 0, stream>>>(xyz, new_xyz, gi);
    point_q_kernel<<<(BATCH * NPOINT * 64) / 256, 256, 0, stream>>>(new_xyz, w0, Q);

    stats0_kernel<<<NBLK, 256, 0, stream>>>(P, Q, gi, partial);
    reduce_stats_kernel<<<64, 256, 0, stream>>>(partial, 64, inv_count, g0, be0, ss + 0);

    chain1_kernel<<<NBLK, 256, 0, stream>>>(P, Q, gi, w1, b1, ss, partial);
    reduce_stats_kernel<<<64, 256, 0, stream>>>(partial, 64, inv_count, g1, be1, ss + 256);

    chain2_kernel<<<NBLK, 256, 0, stream>>>(P, Q, gi, w1, b1, w2, b2, ss, partial, maxy);
    reduce_stats_kernel<<<128, 256, 0, stream>>>(partial, 128, inv_count, g2, be2, ss + 512);

    final_kernel<<<(BATCH * NPOINT * 128) / 256, 256, 0, stream>>>(maxy, ss + 512, out_pts);
}